// Round 3
// baseline (94.452 us; speedup 1.0000x reference)
//
#include <hip/hip_runtime.h>
#include <math.h>

// B=2, L=2048, D=512, N=64 -> M=4096 tokens.
//   y[t,d] = x[t,d] * softplus((x@W1+b1)[t,d]) * s[t]
//   s[t]   = dot(x_t@W2+b2, x_t@W3+b3)
//   exp(delta*A) multiplies h=0 -> contributes zero; A unused.
//
// v3b: resubmission of v3 (round-2 bench died at container acquire — infra).
// Re-tiled fused kernel 64 tokens x 128 d-cols per block (grid 4 x 64).
// Each wave reuses one W1 B-fragment across 4 m-tiles -> w1t L2 traffic
// drops 128 MB -> 32 MB.  s computed redundantly per d-split (cheap MFMA).
// prep_w widened to 80 blocks (k-split 4x) to shrink its serial bubble.
#define DDIM 512

typedef _Float16 f16;
typedef _Float16 f16x4 __attribute__((ext_vector_type(4)));
typedef _Float16 f16x8 __attribute__((ext_vector_type(8)));
typedef float f32x4 __attribute__((ext_vector_type(4)));

__device__ __forceinline__ float softplusf(float v) {
    return (v > 20.0f) ? v : log1pf(__expf(v));
}

// ---------------------------------------------------------------------------
// prep_w: 80 blocks x 256 thr.  Strips of 128k x 32cols.
//   b <  64: W1 strip ws=b>>2 (cols ws*32..+32), k-chunk kc=b&3 -> w1t slabs
//   b < 72 : W2 (2 strips x 4 k-chunks)         -> w23 slabs 0..3
//   b < 80 : W3                                  -> w23 slabs 4..7
// Slab layout (consumer fragment order): dst[(nt*16 + kt)*512 + lane*8 + e]
//   = W[k = kt*32 + (lane>>4)*8 + e][n = nt*16 + (lane&15)]
// ---------------------------------------------------------------------------
__global__ __launch_bounds__(256) void prep_w(
    const float* __restrict__ W1, const float* __restrict__ W2,
    const float* __restrict__ W3, f16* __restrict__ w1t, f16* __restrict__ w23)
{
    __shared__ __align__(16) f16 lt[32][136];
    const int tid  = threadIdx.x;
    const int wb   = blockIdx.x;
    const int wv   = tid >> 6;
    const int lane = tid & 63;
    const int q    = lane >> 4;
    const int l15  = lane & 15;

    const float* src; int srcRS, col0, k0, kt0; f16* dst;
    if (wb < 64) {
        int ws = wb >> 2, kc = wb & 3;
        src = W1; srcRS = DDIM; col0 = ws * 32; k0 = kc * 128; kt0 = kc * 4;
        dst = w1t + (size_t)(ws * 2) * 16 * 512;
    } else if (wb < 72) {
        int i = wb - 64, ws = i >> 2, kc = i & 3;
        src = W2; srcRS = 64; col0 = ws * 32; k0 = kc * 128; kt0 = kc * 4;
        dst = w23 + (size_t)(ws * 2) * 16 * 512;
    } else {
        int i = wb - 72, ws = i >> 2, kc = i & 3;
        src = W3; srcRS = 64; col0 = ws * 32; k0 = kc * 128; kt0 = kc * 4;
        dst = w23 + (size_t)(4 + ws * 2) * 16 * 512;
    }
#pragma unroll
    for (int i = 0; i < 4; ++i) {
        int f  = tid + 256 * i;        // 0..1023
        int k  = f >> 3;               // 0..127
        int c4 = (f & 7) * 4;          // 0..28
        float4 v = *(const float4*)(src + (size_t)(k0 + k) * srcRS + col0 + c4);
        lt[c4 + 0][k] = (f16)v.x; lt[c4 + 1][k] = (f16)v.y;
        lt[c4 + 2][k] = (f16)v.z; lt[c4 + 3][k] = (f16)v.w;
    }
    __syncthreads();
#pragma unroll
    for (int j = 0; j < 2; ++j) {
        int s   = wv * 2 + j;          // 0..7
        int ntL = s >> 2;              // 0..1
        int ktL = s & 3;               // 0..3
        f16x8 vv = *(const f16x8*)&lt[ntL * 16 + l15][ktL * 32 + q * 8];
        *(f16x8*)(dst + (size_t)(ntL * 16 + kt0 + ktL) * 512 + lane * 8) = vv;
    }
}

// ---------------------------------------------------------------------------
// fused_sy: grid (4, M/64) x 512 thr (8 waves).  Block = 64 tokens x 128 d.
// Phase 0: stage x rows -> xs (f16 fragments, full 512 k) + xf (fp32, own
//          128-col chunk only, for epilogue).
// Phase 1: s — wave (mp=wv>>2, nc=wv&3): m-tiles {2mp,2mp+1}, n-chunk nc,
//          BOTH chains (B via w23 slab nc, C via slab 4+nc).  Intra-wave
//          pairing -> shfl-reduce over 16 n -> ps[nc][t].
// Phase 2: tid<64 folds ps -> s_lds[t].
// Phase 3: y-GEMM — wave wv owns ONE n-tile (cB*8+wv), ALL 4 m-tiles: each
//          1KB W1-fragment read feeds 4 MFMAs (4x B-reuse vs v2).
// Phase 4: epilogue in place into xf, coalesced float4 copy-out.
// LDS ~100 KB -> 1 block/CU, 8 waves (2/SIMD), 256 blocks = full GPU.
// ---------------------------------------------------------------------------
__global__ __launch_bounds__(512) void fused_sy(
    const float* __restrict__ x, const f16* __restrict__ w1t,
    const f16* __restrict__ w23, const float* __restrict__ b1,
    const float* __restrict__ b2, const float* __restrict__ b3,
    float* __restrict__ y)
{
    __shared__ __align__(16) f16  xs[64][520];   // 66.5 KB  f16 A-fragments
    __shared__ __align__(16) float xf[64][132];  // 33.8 KB  fp32 x -> y
    __shared__ float ps[4][64];                  // 1 KB s partials per n-chunk
    __shared__ float s_lds[64];

    const int tid  = threadIdx.x;
    const int wv   = tid >> 6;
    const int lane = tid & 63;
    const int q    = lane >> 4;
    const int l15  = lane & 15;
    const int cB   = blockIdx.x;       // 0..3  d-chunk (128 cols)
    const int rB   = blockIdx.y;       // 0..63 token-block (64 rows)
    const int tb   = rB * 64;

    // ---- Phase 0: stage x (coalesced float4; 64 rows x 512 cols) ----
#pragma unroll
    for (int it = 0; it < 16; ++it) {
        int f   = tid + 512 * it;      // 0..8191
        int row = f >> 7;              // 128 float4 per row
        int c4  = (f & 127) * 4;       // 0..508
        float4 v = *(const float4*)(x + (size_t)(tb + row) * DDIM + c4);
        f16x4 h = {(f16)v.x, (f16)v.y, (f16)v.z, (f16)v.w};
        *(f16x4*)&xs[row][c4] = h;
        if (((f >> 5) & 3) == cB)      // own 128-col chunk
            *(float4*)&xf[row][c4 - cB * 128] = v;
    }
    __syncthreads();

    // ---- Phase 1: s chains (wave: 2 m-tiles x n-chunk, both B and C) ----
    {
        const int mp = wv >> 2;        // 0..1
        const int nc = wv & 3;         // 0..3
        const f16* wB = w23 + (size_t)(nc    ) * 16 * 512 + lane * 8;
        const f16* wC = w23 + (size_t)(nc + 4) * 16 * 512 + lane * 8;
        f32x4 aB0 = (f32x4){0.f,0.f,0.f,0.f}, aB1 = (f32x4){0.f,0.f,0.f,0.f};
        f32x4 aC0 = (f32x4){0.f,0.f,0.f,0.f}, aC1 = (f32x4){0.f,0.f,0.f,0.f};
#pragma unroll
        for (int kt = 0; kt < 16; ++kt) {
            f16x8 wBv = *(const f16x8*)(wB + (size_t)kt * 512);
            f16x8 wCv = *(const f16x8*)(wC + (size_t)kt * 512);
            f16x8 a0 = *(const f16x8*)&xs[(2*mp+0)*16 + l15][kt * 32 + q * 8];
            f16x8 a1 = *(const f16x8*)&xs[(2*mp+1)*16 + l15][kt * 32 + q * 8];
            aB0 = __builtin_amdgcn_mfma_f32_16x16x32_f16(a0, wBv, aB0, 0, 0, 0);
            aC0 = __builtin_amdgcn_mfma_f32_16x16x32_f16(a0, wCv, aC0, 0, 0, 0);
            aB1 = __builtin_amdgcn_mfma_f32_16x16x32_f16(a1, wBv, aB1, 0, 0, 0);
            aC1 = __builtin_amdgcn_mfma_f32_16x16x32_f16(a1, wCv, aC1, 0, 0, 0);
        }
        float b2v = b2[nc * 16 + l15];
        float b3v = b3[nc * 16 + l15];
#pragma unroll
        for (int r = 0; r < 4; ++r) {
            float p0 = (aB0[r] + b2v) * (aC0[r] + b3v);
            float p1 = (aB1[r] + b2v) * (aC1[r] + b3v);
            p0 += __shfl_xor(p0, 1); p1 += __shfl_xor(p1, 1);
            p0 += __shfl_xor(p0, 2); p1 += __shfl_xor(p1, 2);
            p0 += __shfl_xor(p0, 4); p1 += __shfl_xor(p1, 4);
            p0 += __shfl_xor(p0, 8); p1 += __shfl_xor(p1, 8);
            if (l15 == 0) {
                ps[nc][(2*mp+0)*16 + q*4 + r] = p0;
                ps[nc][(2*mp+1)*16 + q*4 + r] = p1;
            }
        }
    }
    __syncthreads();

    // ---- Phase 2: fold s partials (tiny; overlaps waves entering phase 3) --
    if (tid < 64)
        s_lds[tid] = ps[0][tid] + ps[1][tid] + ps[2][tid] + ps[3][tid];

    // ---- Phase 3: y-GEMM — wave owns n-tile cB*8+wv, all 4 m-tiles ----
    f32x4 acc0 = (f32x4){0.f,0.f,0.f,0.f}, acc1 = (f32x4){0.f,0.f,0.f,0.f};
    f32x4 acc2 = (f32x4){0.f,0.f,0.f,0.f}, acc3 = (f32x4){0.f,0.f,0.f,0.f};
    const f16* bP = w1t + (size_t)(cB * 8 + wv) * 16 * 512 + lane * 8;
#pragma unroll
    for (int kt = 0; kt < 16; ++kt) {
        f16x8 b  = *(const f16x8*)(bP + (size_t)kt * 512);
        f16x8 a0 = *(const f16x8*)&xs[ 0 + l15][kt * 32 + q * 8];
        f16x8 a1 = *(const f16x8*)&xs[16 + l15][kt * 32 + q * 8];
        f16x8 a2 = *(const f16x8*)&xs[32 + l15][kt * 32 + q * 8];
        f16x8 a3 = *(const f16x8*)&xs[48 + l15][kt * 32 + q * 8];
        acc0 = __builtin_amdgcn_mfma_f32_16x16x32_f16(a0, b, acc0, 0, 0, 0);
        acc1 = __builtin_amdgcn_mfma_f32_16x16x32_f16(a1, b, acc1, 0, 0, 0);
        acc2 = __builtin_amdgcn_mfma_f32_16x16x32_f16(a2, b, acc2, 0, 0, 0);
        acc3 = __builtin_amdgcn_mfma_f32_16x16x32_f16(a3, b, acc3, 0, 0, 0);
    }
    __syncthreads();   // s_lds visible; xf stable for epilogue

    // ---- Phase 4: epilogue in place (each (t,d) owned by exactly 1 lane) ---
    {
        const int dl = wv * 16 + l15;          // 0..127 within chunk
        const float bb = b1[cB * 128 + dl];
#pragma unroll
        for (int r = 0; r < 4; ++r) {
            int t0 = 0*16 + q*4 + r, t1 = 1*16 + q*4 + r;
            int t2 = 2*16 + q*4 + r, t3 = 3*16 + q*4 + r;
            xf[t0][dl] = xf[t0][dl] * softplusf(acc0[r] + bb) * s_lds[t0];
            xf[t1][dl] = xf[t1][dl] * softplusf(acc1[r] + bb) * s_lds[t1];
            xf[t2][dl] = xf[t2][dl] * softplusf(acc2[r] + bb) * s_lds[t2];
            xf[t3][dl] = xf[t3][dl] * softplusf(acc3[r] + bb) * s_lds[t3];
        }
    }
    __syncthreads();

    // ---- copy-out: 64 rows x 128 f32 (own chunk), coalesced float4 ----
#pragma unroll
    for (int it = 0; it < 4; ++it) {
        int f   = tid + 512 * it;      // 0..2047
        int row = f >> 5;              // 32 float4 per row
        int c4  = (f & 31) * 4;        // 0..124
        *(float4*)(y + (size_t)(tb + row) * DDIM + cB * 128 + c4) =
            *(const float4*)&xf[row][c4];
    }
}

// ---------------------------------------------------------------------------
extern "C" void kernel_launch(void* const* d_in, const int* in_sizes, int n_in,
                              void* d_out, int out_size, void* d_ws, size_t ws_size,
                              hipStream_t stream)
{
    (void)n_in; (void)out_size; (void)ws_size;
    const float* x  = (const float*)d_in[0];
    const float* W1 = (const float*)d_in[1];
    const float* b1 = (const float*)d_in[2];
    const float* W2 = (const float*)d_in[3];
    const float* b2 = (const float*)d_in[4];
    const float* W3 = (const float*)d_in[5];
    const float* b3 = (const float*)d_in[6];
    // d_in[7] = A unused (multiplies h=0)
    float* y = (float*)d_out;

    char* ws = (char*)d_ws;
    f16* w1t = (f16*)ws;                    // 512 KB (32 nt x 16 kt slabs)
    f16* w23 = (f16*)(ws + (512 << 10));    // 128 KB (8 nt x 16 kt slabs)

    const int M = in_sizes[0] / DDIM;       // 4096 tokens

    prep_w<<<80, 256, 0, stream>>>(W1, W2, W3, w1t, w23);
    fused_sy<<<dim3(4, M / 64), 512, 0, stream>>>(x, w1t, w23, b1, b2, b3, y);
}